// Round 1
// baseline (127.326 us; speedup 1.0000x reference)
//
#include <hip/hip_runtime.h>
#include <hip/hip_bf16.h>
#include <stdint.h>

typedef unsigned short u16;
typedef __attribute__((ext_vector_type(8))) short short8;
typedef __attribute__((ext_vector_type(8))) __bf16 bf16x8;
typedef __attribute__((ext_vector_type(4))) float f32x4;

constexpr int Bc  = 4;
constexpr int Tc  = 2048;
constexpr int Dc  = 768;
constexpr int Hc  = 12;
constexpr int WINc = 128;

static __device__ __forceinline__ u16 f2bf(float f) {
  union { float f; uint32_t u; } v; v.f = f;
  uint32_t u = v.u;
  return (u16)((u + 0x7fffu + ((u >> 16) & 1u)) >> 16);
}

static __device__ __forceinline__ f32x4 mfma16x16x32(bf16x8 a, bf16x8 b, f32x4 c) {
  return __builtin_amdgcn_mfma_f32_16x16x32_bf16(a, b, c, 0, 0, 0);
}

// ---------------------------------------------------------------- cvt x -> bf16
__global__ __launch_bounds__(256) void cvt_f32_to_bf16(const float* __restrict__ in,
                                                       u16* __restrict__ out) {
  const int i = blockIdx.x * 256 + threadIdx.x;   // grid sized exactly: n/4 threads
  const float4 f = ((const float4*)in)[i];
  union { u16 h[4]; uint2 u; } pk;
  pk.h[0] = f2bf(f.x); pk.h[1] = f2bf(f.y); pk.h[2] = f2bf(f.z); pk.h[3] = f2bf(f.w);
  ((uint2*)out)[i] = pk.u;
}

// ------------------------------------------- W [R][C] f32  ->  WT [C][R] bf16
__global__ __launch_bounds__(256) void transpose_cvt(const float* __restrict__ W,
                                                     u16* __restrict__ WT,
                                                     int R, int C) {
  __shared__ float tile[64][65];
  const int t  = threadIdx.x;
  const int c0 = blockIdx.x * 64, r0 = blockIdx.y * 64;
#pragma unroll
  for (int i = 0; i < 16; ++i) {
    const int e = i * 256 + t;
    const int r = e >> 6, c = e & 63;
    tile[r][c] = W[(size_t)(r0 + r) * C + c0 + c];
  }
  __syncthreads();
#pragma unroll
  for (int i = 0; i < 16; ++i) {
    const int e = i * 256 + t;
    const int r = e >> 6, c = e & 63;
    WT[(size_t)(c0 + r) * R + r0 + c] = f2bf(tile[c][r]);
  }
}

// ---------------------------------------------------------------- GEMM  C = A * B^T
// A: [M][768] bf16 row-major. Bt: [N][768] bf16 row-major (i.e. B transposed).
// 128x128 tile, BK=32, 4 waves (2x2), each wave 64x64 via 4x4 16x16x32 MFMA frags.
// EPI==0: split columns into q/k/v ws buffers laid out [B*H][T][64] bf16.
// EPI==1: write f32 to out [M][768].
template <int EPI>
__global__ __launch_bounds__(256) void gemm_bt(const u16* __restrict__ A,
                                               const u16* __restrict__ Bt,
                                               u16* __restrict__ q_ws,
                                               u16* __restrict__ k_ws,
                                               u16* __restrict__ v_ws,
                                               float* __restrict__ fout) {
  __shared__ u16 As[128][32];
  __shared__ u16 Bs[128][32];
  const int t  = threadIdx.x;
  const int w  = t >> 6, l = t & 63;
  const int lr = l & 15, lh = l >> 4;
  const int wm = w >> 1, wn = w & 1;
  const int m0 = blockIdx.y * 128, n0 = blockIdx.x * 128;

  f32x4 acc[4][4];
#pragma unroll
  for (int mi = 0; mi < 4; ++mi)
#pragma unroll
    for (int ni = 0; ni < 4; ++ni) acc[mi][ni] = f32x4{0.f, 0.f, 0.f, 0.f};

  const u16* aP = A  + (size_t)(m0 + (t >> 2)) * 768 + (t & 3) * 8;
  const u16* bP = Bt + (size_t)(n0 + (t >> 2)) * 768 + (t & 3) * 8;

  for (int kt = 0; kt < 24; ++kt) {
    const int ko = kt * 32;
    short8 a0 = *(const short8*)(aP + ko);
    short8 a1 = *(const short8*)(aP + ko + 64 * 768);
    short8 b0 = *(const short8*)(bP + ko);
    short8 b1 = *(const short8*)(bP + ko + 64 * 768);
    __syncthreads();
    *(short8*)((char*)As + t * 16)        = a0;
    *(short8*)((char*)As + t * 16 + 4096) = a1;
    *(short8*)((char*)Bs + t * 16)        = b0;
    *(short8*)((char*)Bs + t * 16 + 4096) = b1;
    __syncthreads();

    bf16x8 af[4], bfr[4];
#pragma unroll
    for (int mi = 0; mi < 4; ++mi)
      af[mi] = *(const bf16x8*)&As[wm * 64 + mi * 16 + lr][lh * 8];
#pragma unroll
    for (int ni = 0; ni < 4; ++ni)
      bfr[ni] = *(const bf16x8*)&Bs[wn * 64 + ni * 16 + lr][lh * 8];
#pragma unroll
    for (int mi = 0; mi < 4; ++mi)
#pragma unroll
      for (int ni = 0; ni < 4; ++ni)
        acc[mi][ni] = mfma16x16x32(af[mi], bfr[ni], acc[mi][ni]);
  }

  if (EPI == 0) {
#pragma unroll
    for (int mi = 0; mi < 4; ++mi)
#pragma unroll
      for (int ni = 0; ni < 4; ++ni) {
        const int col   = n0 + wn * 64 + ni * 16 + lr;
        const int which = col / 768;
        const int rem   = col - which * 768;
        const int h     = rem >> 6, d = rem & 63;
        u16* dst = (which == 0) ? q_ws : ((which == 1) ? k_ws : v_ws);
#pragma unroll
        for (int r = 0; r < 4; ++r) {
          const int m  = m0 + wm * 64 + mi * 16 + lh * 4 + r;
          const int bb = m >> 11, tt = m & 2047;   // T = 2048
          dst[(((size_t)(bb * Hc + h) * Tc + tt) << 6) + d] = f2bf(acc[mi][ni][r]);
        }
      }
  } else {
#pragma unroll
    for (int mi = 0; mi < 4; ++mi)
#pragma unroll
      for (int ni = 0; ni < 4; ++ni) {
        const int col = n0 + wn * 64 + ni * 16 + lr;
#pragma unroll
        for (int r = 0; r < 4; ++r) {
          const int m = m0 + wm * 64 + mi * 16 + lh * 4 + r;
          fout[(size_t)m * 768 + col] = acc[mi][ni][r];
        }
      }
  }
}

// ----------------------------------------------- sliding-window flash attention
// Q/K/V ws: [B*H][T][64] bf16. Out (attn) ws: [B][T][H*64] bf16.
// Block = 256 threads (4 waves) handles one (b,h) and 64 queries.
// Wave w owns 16 query rows. Key tiles of 64, online softmax.
__global__ __launch_bounds__(256) void swa_attn(const u16* __restrict__ Q,
                                                const u16* __restrict__ Kk,
                                                const u16* __restrict__ V,
                                                u16* __restrict__ Out) {
  __shared__ u16 Qs[64][72];
  __shared__ u16 Ks[64][72];
  __shared__ u16 Vt[64][72];      // V transposed: Vt[d][key]
  __shared__ u16 Ps[4][16][72];   // per-wave P tile (16 q x 64 k)

  const int t  = threadIdx.x;
  const int w  = t >> 6, l = t & 63;
  const int lr = l & 15, lh = l >> 4;
  const int bh = blockIdx.y;
  const int q0 = blockIdx.x * 64;
  const size_t head_base = (size_t)bh * Tc * 64;

  {  // stage Q (64 rows x 64 cols)
    const int row = t >> 2, c = (t & 3) * 16;
    const short8* src = (const short8*)(Q + head_base + (size_t)(q0 + row) * 64 + c);
    *(short8*)&Qs[row][c]     = src[0];
    *(short8*)&Qs[row][c + 8] = src[1];
  }

  float m_r[4], l_r[4];
  f32x4 Oa[4];
#pragma unroll
  for (int r = 0; r < 4; ++r) { m_r[r] = -1e30f; l_r[r] = 0.f; }
#pragma unroll
  for (int n = 0; n < 4; ++n) Oa[n] = f32x4{0.f, 0.f, 0.f, 0.f};

  const int kb_lo = (q0 >= WINc) ? q0 - WINc : 0;
  for (int kb = kb_lo; kb <= q0; kb += 64) {
    __syncthreads();   // also covers Q-staging visibility on first iter
    {  // stage K tile and V tile (transposed into Vt)
      const int row = t >> 2, c = (t & 3) * 16;
      const short8* ksrc = (const short8*)(Kk + head_base + (size_t)(kb + row) * 64 + c);
      *(short8*)&Ks[row][c]     = ksrc[0];
      *(short8*)&Ks[row][c + 8] = ksrc[1];
      const short8* vsrc = (const short8*)(V + head_base + (size_t)(kb + row) * 64 + c);
      short8 v0 = vsrc[0], v1 = vsrc[1];
#pragma unroll
      for (int j = 0; j < 8; ++j) {
        Vt[c + j][row]     = (u16)v0[j];
        Vt[c + 8 + j][row] = (u16)v1[j];
      }
    }
    __syncthreads();

    bf16x8 qa0 = *(const bf16x8*)&Qs[w * 16 + lr][lh * 8];
    bf16x8 qa1 = *(const bf16x8*)&Qs[w * 16 + lr][32 + lh * 8];

    f32x4 s[4];
#pragma unroll
    for (int sub = 0; sub < 4; ++sub) {
      bf16x8 kb0 = *(const bf16x8*)&Ks[sub * 16 + lr][lh * 8];
      bf16x8 kb1 = *(const bf16x8*)&Ks[sub * 16 + lr][32 + lh * 8];
      f32x4 z = f32x4{0.f, 0.f, 0.f, 0.f};
      z = mfma16x16x32(qa0, kb0, z);
      z = mfma16x16x32(qa1, kb1, z);
      s[sub] = z;
    }

    // mask + scale (allowed: qi-128 <= kj <= qi)
    const int qbase = q0 + w * 16 + lh * 4;
#pragma unroll
    for (int sub = 0; sub < 4; ++sub) {
      const int kj = kb + sub * 16 + lr;
#pragma unroll
      for (int r = 0; r < 4; ++r) {
        const int qi = qbase + r;
        const bool ok = (kj <= qi) && (kj + WINc >= qi);
        s[sub][r] = ok ? s[sub][r] * 0.125f : -1e30f;
      }
    }

    // row max across 64 keys of this tile
    float mt[4];
#pragma unroll
    for (int r = 0; r < 4; ++r)
      mt[r] = fmaxf(fmaxf(s[0][r], s[1][r]), fmaxf(s[2][r], s[3][r]));
#pragma unroll
    for (int msk = 1; msk < 16; msk <<= 1)
#pragma unroll
      for (int r = 0; r < 4; ++r)
        mt[r] = fmaxf(mt[r], __shfl_xor(mt[r], msk, 64));

    float al[4];
#pragma unroll
    for (int r = 0; r < 4; ++r) {
      const float mn = fmaxf(m_r[r], mt[r]);
      al[r] = __expf(m_r[r] - mn);
      m_r[r] = mn;
    }

    // p = exp(s - m), row sum
    float rs[4] = {0.f, 0.f, 0.f, 0.f};
#pragma unroll
    for (int sub = 0; sub < 4; ++sub)
#pragma unroll
      for (int r = 0; r < 4; ++r) {
        const float p = __expf(s[sub][r] - m_r[r]);
        s[sub][r] = p;
        rs[r] += p;
      }
#pragma unroll
    for (int msk = 1; msk < 16; msk <<= 1)
#pragma unroll
      for (int r = 0; r < 4; ++r)
        rs[r] += __shfl_xor(rs[r], msk, 64);
#pragma unroll
    for (int r = 0; r < 4; ++r) l_r[r] = l_r[r] * al[r] + rs[r];

    // rescale O
#pragma unroll
    for (int n = 0; n < 4; ++n)
#pragma unroll
      for (int r = 0; r < 4; ++r) Oa[n][r] *= al[r];

    // P -> LDS (wave-private), re-layout for PV A-operand
#pragma unroll
    for (int sub = 0; sub < 4; ++sub)
#pragma unroll
      for (int r = 0; r < 4; ++r)
        Ps[w][lh * 4 + r][sub * 16 + lr] = f2bf(s[sub][r]);

    // PV: O += P (16x64) * V (64x64)
#pragma unroll
    for (int ks = 0; ks < 2; ++ks) {
      bf16x8 pa = *(const bf16x8*)&Ps[w][lr][ks * 32 + lh * 8];
#pragma unroll
      for (int n = 0; n < 4; ++n) {
        bf16x8 vb = *(const bf16x8*)&Vt[n * 16 + lr][ks * 32 + lh * 8];
        Oa[n] = mfma16x16x32(pa, vb, Oa[n]);
      }
    }
  }

  // epilogue: write attn out [B][T][H*64] bf16
  const int bb = bh / Hc, h = bh - bb * Hc;
#pragma unroll
  for (int n = 0; n < 4; ++n)
#pragma unroll
    for (int r = 0; r < 4; ++r) {
      const float val = Oa[n][r] / l_r[r];
      const int ti = q0 + w * 16 + lh * 4 + r;
      Out[((size_t)(bb * Tc + ti)) * 768 + h * 64 + n * 16 + lr] = f2bf(val);
    }
}

// -----------------------------------------------------------------------------
extern "C" void kernel_launch(void* const* d_in, const int* in_sizes, int n_in,
                              void* d_out, int out_size, void* d_ws, size_t ws_size,
                              hipStream_t stream) {
  (void)in_sizes; (void)n_in; (void)out_size; (void)ws_size;
  const float* x    = (const float*)d_in[0];
  const float* Wqkv = (const float*)d_in[1];
  const float* Wout = (const float*)d_in[2];
  float* out = (float*)d_out;

  u16* ws    = (u16*)d_ws;
  u16* xb    = ws;                     // 6291456 elems (x as bf16)
  u16* wqkvT = xb + 6291456;           // 1769472
  u16* woutT = wqkvT + 1769472;        // 589824
  u16* qws   = woutT + 589824;         // 6291456
  u16* kws   = qws + 6291456;          // 6291456
  u16* vws   = kws + 6291456;          // 6291456
  u16* aws   = xb;                     // attn out aliases xb (dead after gemm1)

  cvt_f32_to_bf16<<<6144, 256, 0, stream>>>(x, xb);                       // 6291456/4
  transpose_cvt<<<dim3(36, 12), 256, 0, stream>>>(Wqkv, wqkvT, 768, 2304);
  transpose_cvt<<<dim3(12, 12), 256, 0, stream>>>(Wout, woutT, 768, 768);
  gemm_bt<0><<<dim3(18, 64), 256, 0, stream>>>(xb, wqkvT, qws, kws, vws, nullptr);
  swa_attn<<<dim3(32, 48), 256, 0, stream>>>(qws, kws, vws, aws);
  gemm_bt<1><<<dim3(6, 64), 256, 0, stream>>>(aws, woutT, nullptr, nullptr, nullptr, out);
}

// Round 2
// 113.552 us; speedup vs baseline: 1.1213x; 1.1213x over previous
//
#include <hip/hip_runtime.h>
#include <hip/hip_bf16.h>
#include <stdint.h>

typedef unsigned short u16;
typedef __attribute__((ext_vector_type(8))) short short8;
typedef __attribute__((ext_vector_type(8))) __bf16 bf16x8;
typedef __attribute__((ext_vector_type(4))) float f32x4;

constexpr int Bc  = 4;
constexpr int Tc  = 2048;
constexpr int Dc  = 768;
constexpr int Hc  = 12;
constexpr int WINc = 128;

static __device__ __forceinline__ u16 f2bf(float f) {
  union { float f; uint32_t u; } v; v.f = f;
  uint32_t u = v.u;
  return (u16)((u + 0x7fffu + ((u >> 16) & 1u)) >> 16);
}

static __device__ __forceinline__ f32x4 mfma16x16x32(bf16x8 a, bf16x8 b, f32x4 c) {
  return __builtin_amdgcn_mfma_f32_16x16x32_bf16(a, b, c, 0, 0, 0);
}

#define GLOAD_LDS16(gsrc, ldst)                                                \
  __builtin_amdgcn_global_load_lds(                                            \
      (const __attribute__((address_space(1))) void*)(gsrc),                   \
      (__attribute__((address_space(3))) void*)(ldst), 16, 0, 0)

// ---------------------------------------------------------------- cvt x -> bf16
__global__ __launch_bounds__(256) void cvt_f32_to_bf16(const float* __restrict__ in,
                                                       u16* __restrict__ out) {
  const int i = blockIdx.x * 256 + threadIdx.x;   // grid sized exactly: n/4 threads
  const float4 f = ((const float4*)in)[i];
  union { u16 h[4]; uint2 u; } pk;
  pk.h[0] = f2bf(f.x); pk.h[1] = f2bf(f.y); pk.h[2] = f2bf(f.z); pk.h[3] = f2bf(f.w);
  ((uint2*)out)[i] = pk.u;
}

// ------------------------------------------- W [R][C] f32  ->  WT [C][R] bf16
__global__ __launch_bounds__(256) void transpose_cvt(const float* __restrict__ W,
                                                     u16* __restrict__ WT,
                                                     int R, int C) {
  __shared__ float tile[64][65];
  const int t  = threadIdx.x;
  const int c0 = blockIdx.x * 64, r0 = blockIdx.y * 64;
#pragma unroll
  for (int i = 0; i < 16; ++i) {
    const int e = i * 256 + t;
    const int r = e >> 6, c = e & 63;
    tile[r][c] = W[(size_t)(r0 + r) * C + c0 + c];
  }
  __syncthreads();
#pragma unroll
  for (int i = 0; i < 16; ++i) {
    const int e = i * 256 + t;
    const int r = e >> 6, c = e & 63;
    WT[(size_t)(c0 + r) * R + r0 + c] = f2bf(tile[c][r]);
  }
}

// ---------------------------------------------------------------- GEMM  C = A * B^T
// A: [M][768] bf16 row-major. Bt: [N][768] bf16 row-major (i.e. B transposed).
// 128x128 tile, BK=32, 4 waves (2x2), each wave 64x64 via 4x4 16x16x32 MFMA frags.
// Staging via global_load_lds width=16 (linear LDS layout, wave-uniform dest base).
// EPI==0: split columns into q/k/v ws buffers laid out [B*H][T][64] bf16.
// EPI==1: write f32 to out [M][768].
template <int EPI>
__global__ __launch_bounds__(256) void gemm_bt(const u16* __restrict__ A,
                                               const u16* __restrict__ Bt,
                                               u16* __restrict__ q_ws,
                                               u16* __restrict__ k_ws,
                                               u16* __restrict__ v_ws,
                                               float* __restrict__ fout) {
  __shared__ u16 As[128][32];
  __shared__ u16 Bs[128][32];
  const int t  = threadIdx.x;
  const int w  = t >> 6, l = t & 63;
  const int lr = l & 15, lh = l >> 4;
  const int wm = w >> 1, wn = w & 1;
  const int m0 = blockIdx.y * 128, n0 = blockIdx.x * 128;

  f32x4 acc[4][4];
#pragma unroll
  for (int mi = 0; mi < 4; ++mi)
#pragma unroll
    for (int ni = 0; ni < 4; ++ni) acc[mi][ni] = f32x4{0.f, 0.f, 0.f, 0.f};

  // staging: issue j covers rows [j*64, j*64+64); wave w owns 16 rows within it;
  // lane l -> row (l>>2), elem col (l&3)*8. LDS dest is wave-uniform base.
  const int srow = l >> 2;
  const int scol = (l & 3) * 8;
  const u16* aP = A  + (size_t)(m0 + w * 16 + srow) * 768 + scol;
  const u16* bP = Bt + (size_t)(n0 + w * 16 + srow) * 768 + scol;
  char* asB = (char*)As + w * 1024;
  char* bsB = (char*)Bs + w * 1024;

  for (int kt = 0; kt < 24; ++kt) {
    const int ko = kt * 32;
    __syncthreads();   // previous compute done before overwrite
    GLOAD_LDS16(aP + ko,            asB);
    GLOAD_LDS16(aP + ko + 64 * 768, asB + 4096);
    GLOAD_LDS16(bP + ko,            bsB);
    GLOAD_LDS16(bP + ko + 64 * 768, bsB + 4096);
    __syncthreads();   // compiler drains vmcnt before this barrier

    bf16x8 af[4], bfr[4];
#pragma unroll
    for (int mi = 0; mi < 4; ++mi)
      af[mi] = *(const bf16x8*)&As[wm * 64 + mi * 16 + lr][lh * 8];
#pragma unroll
    for (int ni = 0; ni < 4; ++ni)
      bfr[ni] = *(const bf16x8*)&Bs[wn * 64 + ni * 16 + lr][lh * 8];
#pragma unroll
    for (int mi = 0; mi < 4; ++mi)
#pragma unroll
      for (int ni = 0; ni < 4; ++ni)
        acc[mi][ni] = mfma16x16x32(af[mi], bfr[ni], acc[mi][ni]);
  }

  if (EPI == 0) {
#pragma unroll
    for (int mi = 0; mi < 4; ++mi)
#pragma unroll
      for (int ni = 0; ni < 4; ++ni) {
        const int col   = n0 + wn * 64 + ni * 16 + lr;
        const int which = col / 768;
        const int rem   = col - which * 768;
        const int h     = rem >> 6, d = rem & 63;
        u16* dst = (which == 0) ? q_ws : ((which == 1) ? k_ws : v_ws);
#pragma unroll
        for (int r = 0; r < 4; ++r) {
          const int m  = m0 + wm * 64 + mi * 16 + lh * 4 + r;
          const int bb = m >> 11, tt = m & 2047;   // T = 2048
          dst[(((size_t)(bb * Hc + h) * Tc + tt) << 6) + d] = f2bf(acc[mi][ni][r]);
        }
      }
  } else {
#pragma unroll
    for (int mi = 0; mi < 4; ++mi)
#pragma unroll
      for (int ni = 0; ni < 4; ++ni) {
        const int col = n0 + wn * 64 + ni * 16 + lr;
#pragma unroll
        for (int r = 0; r < 4; ++r) {
          const int m = m0 + wm * 64 + mi * 16 + lh * 4 + r;
          fout[(size_t)m * 768 + col] = acc[mi][ni][r];
        }
      }
  }
}

// ----------------------------------------------- sliding-window flash attention
// Q/K/V ws: [B*H][T][64] bf16. Out (attn) ws: [B][T][H*64] bf16.
// Block = 256 threads (4 waves) handles one (b,h) and 64 queries.
// Wave w owns 16 query rows. Key tiles of 64, online softmax.
__global__ __launch_bounds__(256) void swa_attn(const u16* __restrict__ Q,
                                                const u16* __restrict__ Kk,
                                                const u16* __restrict__ V,
                                                u16* __restrict__ Out) {
  __shared__ u16 Qs[64][72];
  __shared__ u16 Ks[64][72];
  __shared__ u16 Vt[64][72];      // V transposed: Vt[d][key]
  __shared__ u16 Ps[4][16][72];   // per-wave P tile (16 q x 64 k)

  const int t  = threadIdx.x;
  const int w  = t >> 6, l = t & 63;
  const int lr = l & 15, lh = l >> 4;
  const int bh = blockIdx.y;
  const int q0 = blockIdx.x * 64;
  const size_t head_base = (size_t)bh * Tc * 64;

  {  // stage Q (64 rows x 64 cols)
    const int row = t >> 2, c = (t & 3) * 16;
    const short8* src = (const short8*)(Q + head_base + (size_t)(q0 + row) * 64 + c);
    *(short8*)&Qs[row][c]     = src[0];
    *(short8*)&Qs[row][c + 8] = src[1];
  }

  float m_r[4], l_r[4];
  f32x4 Oa[4];
#pragma unroll
  for (int r = 0; r < 4; ++r) { m_r[r] = -1e30f; l_r[r] = 0.f; }
#pragma unroll
  for (int n = 0; n < 4; ++n) Oa[n] = f32x4{0.f, 0.f, 0.f, 0.f};

  const int kb_lo = (q0 >= WINc) ? q0 - WINc : 0;
  for (int kb = kb_lo; kb <= q0; kb += 64) {
    __syncthreads();   // also covers Q-staging visibility on first iter
    {  // stage K tile and V tile (transposed into Vt)
      const int row = t >> 2, c = (t & 3) * 16;
      const short8* ksrc = (const short8*)(Kk + head_base + (size_t)(kb + row) * 64 + c);
      *(short8*)&Ks[row][c]     = ksrc[0];
      *(short8*)&Ks[row][c + 8] = ksrc[1];
      const short8* vsrc = (const short8*)(V + head_base + (size_t)(kb + row) * 64 + c);
      short8 v0 = vsrc[0], v1 = vsrc[1];
#pragma unroll
      for (int j = 0; j < 8; ++j) {
        Vt[c + j][row]     = (u16)v0[j];
        Vt[c + 8 + j][row] = (u16)v1[j];
      }
    }
    __syncthreads();

    bf16x8 qa0 = *(const bf16x8*)&Qs[w * 16 + lr][lh * 8];
    bf16x8 qa1 = *(const bf16x8*)&Qs[w * 16 + lr][32 + lh * 8];

    f32x4 s[4];
#pragma unroll
    for (int sub = 0; sub < 4; ++sub) {
      bf16x8 kb0 = *(const bf16x8*)&Ks[sub * 16 + lr][lh * 8];
      bf16x8 kb1 = *(const bf16x8*)&Ks[sub * 16 + lr][32 + lh * 8];
      f32x4 z = f32x4{0.f, 0.f, 0.f, 0.f};
      z = mfma16x16x32(qa0, kb0, z);
      z = mfma16x16x32(qa1, kb1, z);
      s[sub] = z;
    }

    // mask + scale (allowed: qi-128 <= kj <= qi)
    const int qbase = q0 + w * 16 + lh * 4;
#pragma unroll
    for (int sub = 0; sub < 4; ++sub) {
      const int kj = kb + sub * 16 + lr;
#pragma unroll
      for (int r = 0; r < 4; ++r) {
        const int qi = qbase + r;
        const bool ok = (kj <= qi) && (kj + WINc >= qi);
        s[sub][r] = ok ? s[sub][r] * 0.125f : -1e30f;
      }
    }

    // row max across 64 keys of this tile
    float mt[4];
#pragma unroll
    for (int r = 0; r < 4; ++r)
      mt[r] = fmaxf(fmaxf(s[0][r], s[1][r]), fmaxf(s[2][r], s[3][r]));
#pragma unroll
    for (int msk = 1; msk < 16; msk <<= 1)
#pragma unroll
      for (int r = 0; r < 4; ++r)
        mt[r] = fmaxf(mt[r], __shfl_xor(mt[r], msk, 64));

    float al[4];
#pragma unroll
    for (int r = 0; r < 4; ++r) {
      const float mn = fmaxf(m_r[r], mt[r]);
      al[r] = __expf(m_r[r] - mn);
      m_r[r] = mn;
    }

    // p = exp(s - m), row sum
    float rs[4] = {0.f, 0.f, 0.f, 0.f};
#pragma unroll
    for (int sub = 0; sub < 4; ++sub)
#pragma unroll
      for (int r = 0; r < 4; ++r) {
        const float p = __expf(s[sub][r] - m_r[r]);
        s[sub][r] = p;
        rs[r] += p;
      }
#pragma unroll
    for (int msk = 1; msk < 16; msk <<= 1)
#pragma unroll
      for (int r = 0; r < 4; ++r)
        rs[r] += __shfl_xor(rs[r], msk, 64);
#pragma unroll
    for (int r = 0; r < 4; ++r) l_r[r] = l_r[r] * al[r] + rs[r];

    // rescale O
#pragma unroll
    for (int n = 0; n < 4; ++n)
#pragma unroll
      for (int r = 0; r < 4; ++r) Oa[n][r] *= al[r];

    // P -> LDS (wave-private), re-layout for PV A-operand
#pragma unroll
    for (int sub = 0; sub < 4; ++sub)
#pragma unroll
      for (int r = 0; r < 4; ++r)
        Ps[w][lh * 4 + r][sub * 16 + lr] = f2bf(s[sub][r]);

    // PV: O += P (16x64) * V (64x64)
#pragma unroll
    for (int ks = 0; ks < 2; ++ks) {
      bf16x8 pa = *(const bf16x8*)&Ps[w][lr][ks * 32 + lh * 8];
#pragma unroll
      for (int n = 0; n < 4; ++n) {
        bf16x8 vb = *(const bf16x8*)&Vt[n * 16 + lr][ks * 32 + lh * 8];
        Oa[n] = mfma16x16x32(pa, vb, Oa[n]);
      }
    }
  }

  // epilogue: write attn out [B][T][H*64] bf16
  const int bb = bh / Hc, h = bh - bb * Hc;
#pragma unroll
  for (int n = 0; n < 4; ++n)
#pragma unroll
    for (int r = 0; r < 4; ++r) {
      const float val = Oa[n][r] / l_r[r];
      const int ti = q0 + w * 16 + lh * 4 + r;
      Out[((size_t)(bb * Tc + ti)) * 768 + h * 64 + n * 16 + lr] = f2bf(val);
    }
}

// -----------------------------------------------------------------------------
extern "C" void kernel_launch(void* const* d_in, const int* in_sizes, int n_in,
                              void* d_out, int out_size, void* d_ws, size_t ws_size,
                              hipStream_t stream) {
  (void)in_sizes; (void)n_in; (void)out_size; (void)ws_size;
  const float* x    = (const float*)d_in[0];
  const float* Wqkv = (const float*)d_in[1];
  const float* Wout = (const float*)d_in[2];
  float* out = (float*)d_out;

  u16* ws    = (u16*)d_ws;
  u16* xb    = ws;                     // 6291456 elems (x as bf16)
  u16* wqkvT = xb + 6291456;           // 1769472
  u16* woutT = wqkvT + 1769472;        // 589824
  u16* qws   = woutT + 589824;         // 6291456
  u16* kws   = qws + 6291456;          // 6291456
  u16* vws   = kws + 6291456;          // 6291456
  u16* aws   = xb;                     // attn out aliases xb (dead after gemm1)

  cvt_f32_to_bf16<<<6144, 256, 0, stream>>>(x, xb);                       // 6291456/4
  transpose_cvt<<<dim3(36, 12), 256, 0, stream>>>(Wqkv, wqkvT, 768, 2304);
  transpose_cvt<<<dim3(12, 12), 256, 0, stream>>>(Wout, woutT, 768, 768);
  gemm_bt<0><<<dim3(18, 64), 256, 0, stream>>>(xb, wqkvT, qws, kws, vws, nullptr);
  swa_attn<<<dim3(32, 48), 256, 0, stream>>>(qws, kws, vws, aws);
  gemm_bt<1><<<dim3(6, 64), 256, 0, stream>>>(aws, woutT, nullptr, nullptr, nullptr, out);
}